// Round 4
// baseline (349.374 us; speedup 1.0000x reference)
//
#include <hip/hip_runtime.h>
#include <hip/hip_bf16.h>

// CRF forward (torchcrf, reduction='sum') on MI355X. T=512, B=256, K=128.
// Denominator: 511 sequential steps of s' = (s @ E) * exp(em_t), E = exp(trans)
// hoisted to VGPRs (linear domain -> FMAs, no per-pair exp). Deferred renorm:
// partial sums written at t%4==0 (pre-barrier), applied at t+1 by folding
// rcp(tot) into the emission multiply; log(tot) accumulated in fp64. Exactly
// ONE barrier per step.
// Mask: prefix length L computed once in the numerator phase -> recurrence loop
// has no mask access (benchmark mask is all-ones; prefix-contiguous supported).
// Layout: 1 chain/block (256 blocks ~ 256 CUs), 512 threads (2 waves/SIMD TLP).
// Thread (j=tid>>2, q=tid&3): quarter-dot, 32 FMA, E-quarter-column in 32 VGPRs.
// s[128] ping-pongs in LDS with SKEWED quarters (quarter q at float offset q*36,
// 144B stride): the 4 broadcast float4 addresses per ds_read_b128 hit 16 distinct
// banks (linear layout was a 4-way same-bank conflict). Writes also conflict-free.
// exp(em) computed one step ahead; em prefetch depth 6 (~900cy HBM cover).

#define TT 512
#define BB 256
#define KK 128
#define TB 32768  // BB*KK

__global__ __launch_bounds__(512) void crf_main(
    const float* __restrict__ em,               // [T,B,K]
    const int* __restrict__ tags_raw,           // int32 or int64 [T,B] (detected)
    const unsigned char* __restrict__ mask_raw, // bool bytes or int32 [T,B] (detected)
    const float* __restrict__ startt,           // [K]
    const float* __restrict__ endt,             // [K]
    const float* __restrict__ trans,            // [K,K]
    double* __restrict__ acc)                   // ws accumulator (memset 0)
{
  const int b = blockIdx.x;
  const int tid = threadIdx.x;
  const int j = tid >> 2;        // 0..127 output tag
  const int q = tid & 3;         // quarter of K_prev axis
  const int wid = tid >> 6;      // wave 0..7
  const int qown = j >> 5;       // which quad lane stores s[j]

  __shared__ __align__(16) float srep[2][144];   // skewed: quarter q at [q*36, q*36+32)
  __shared__ __align__(16) float wavesum[16];
  __shared__ int sflags[4];
  __shared__ unsigned char smask[TT];

  // ---- dtype detection ----
  // tags int64 (jax x64): odd int32 words all zero (tags<128). int32: random tags.
  {
    int wv = (tid < 64) ? tags_raw[2 * tid + 1] : 0;
    unsigned long long bal = __ballot(wv != 0);
    if (tid == 0) {
      sflags[0] = (bal == 0ull) ? 1 : 0;        // 1 => int64 tags
      sflags[1] = (mask_raw[1] != 0) ? 0 : 1;   // 1 => int32 mask
    }
  }
  __syncthreads();
  const bool tags64 = (sflags[0] != 0);
  const bool mask32 = (sflags[1] != 0);
  const int* mask_i = (const int*)mask_raw;

  auto get_tag = [&](int t) -> int {
    int idx = t * BB + b;
    return tags64 ? tags_raw[2 * idx] : tags_raw[idx];
  };

  // ---- mask column -> LDS (one pass; used only for numerator / L) ----
  {
    int idx = tid * BB + b;
    bool m = mask32 ? (mask_i[idx] != 0) : (mask_raw[idx] != 0);
    smask[tid] = m ? 1 : 0;
  }
  __syncthreads();

  // ---- numerator: gold path score (one t per thread; prefix-contiguous mask) ----
  float ncon = 0.f, mcnt = 0.f;
  {
    const int t = tid;
    int ct = get_tag(t);
    bool m = (smask[t] != 0);
    if (m) mcnt = 1.f;
    if (t == 0) {
      ncon = startt[ct] + em[(size_t)b * KK + ct];
    } else if (m) {
      int pt = get_tag(t - 1);
      ncon = trans[pt * KK + ct] + em[((size_t)t * BB + b) * KK + ct];
    }
  }
  #pragma unroll
  for (int mm = 1; mm < 64; mm <<= 1) {
    ncon += __shfl_xor(ncon, mm, 64);
    mcnt += __shfl_xor(mcnt, mm, 64);
  }
  if ((tid & 63) == 0) {
    wavesum[wid] = ncon;
    wavesum[8 + wid] = mcnt;
  }
  __syncthreads();
  float num_b = 0.f;                     // live only in tid 0
  if (tid == 0) {
    float ns = 0.f, ms = 0.f;
    #pragma unroll
    for (int wv = 0; wv < 8; ++wv) { ns += wavesum[wv]; ms += wavesum[8 + wv]; }
    int L = (int)(ms + 0.5f);
    num_b = ns + endt[get_tag(L - 1)];   // mask[0] always true
    sflags[2] = L;
  }

  // ---- denominator prologue ----
  float col[32];                          // E[q*32+i][j] = exp(trans[...])
  const int bi = q * 32;
  #pragma unroll
  for (int i = 0; i < 32; ++i)
    col[i] = __expf(trans[(bi + i) * KK + j]);

  const float* emb = em + (size_t)b * KK + j;
  float e0 = __expf(startt[j] + emb[0]);
  if (q == qown) srep[0][j + 4 * qown] = e0;

  // em pipeline: pex = exp(em[t]); e1..e5 = raw em[t+1..t+5]
  float pex = __expf(emb[(size_t)1 * TB]);
  float e1 = emb[(size_t)2 * TB];
  float e2 = emb[(size_t)3 * TB];
  float e3 = emb[(size_t)4 * TB];
  float e4 = emb[(size_t)5 * TB];
  float e5 = emb[(size_t)6 * TB];
  __syncthreads();
  const int L = sflags[2];

  int cur = 0;
  double Cacc = 0.0;                      // used only by tid 0

  for (int t = 1; t < L; ++t) {
    float ecur = pex;                     // exp(em[t]) ready (off critical path)
    pex = __expf(e1);
    e1 = e2; e2 = e3; e3 = e4; e4 = e5;
    int tp = t + 6; if (tp > TT - 1) tp = TT - 1;
    e5 = emb[(size_t)tp * TB];

    // quarter dot: sum_{i in [q*32,q*32+32)} s[i] * E[i][j]
    const float4* sp = reinterpret_cast<const float4*>(&srep[cur][q * 36]);
    float a0 = 0.f, a1 = 0.f, a2 = 0.f, a3 = 0.f;
    #pragma unroll
    for (int ii = 0; ii < 8; ++ii) {
      float4 s4 = sp[ii];                 // 4 bcast addrs -> 16 distinct banks (skew)
      a0 = fmaf(s4.x, col[4 * ii + 0], a0);
      a1 = fmaf(s4.y, col[4 * ii + 1], a1);
      a2 = fmaf(s4.z, col[4 * ii + 2], a2);
      a3 = fmaf(s4.w, col[4 * ii + 3], a3);
    }
    float v = (a0 + a1) + (a2 + a3);
    v += __shfl_xor(v, 1, 64);            // intra-quad combine (cheap)
    v += __shfl_xor(v, 2, 64);
    float w = v * ecur;

    if ((t & 3) == 1 && t != 1) {
      // apply deferred normalizer written at t-1 (read is post-barrier of t-1)
      float4 wa = *reinterpret_cast<const float4*>(&wavesum[0]);
      float4 wb = *reinterpret_cast<const float4*>(&wavesum[4]);
      float tot = ((wa.x + wa.y) + (wa.z + wa.w)) + ((wb.x + wb.y) + (wb.z + wb.w));
      if (tid == 0) Cacc += (double)__logf(tot);
      w *= __builtin_amdgcn_rcpf(tot);    // eps telescopes into next log window
    }
    if ((t & 3) == 0) {
      // publish partial sums for application at t+1 (pre-barrier write)
      float r = w;
      r += __shfl_xor(r, 4, 64);
      r += __shfl_xor(r, 8, 64);
      r += __shfl_xor(r, 16, 64);
      r += __shfl_xor(r, 32, 64);
      if ((tid & 63) == 0) wavesum[wid] = r;
    }
    if (q == qown) srep[cur ^ 1][j + 4 * qown] = w;
    __syncthreads();                      // the ONLY barrier per step
    cur ^= 1;
  }

  // ---- final: den = Cacc + log(sum_j s[j]*exp(end[j])) ----
  float x = srep[cur][j + 4 * qown] * __expf(endt[j]);
  x += __shfl_xor(x, 4, 64);
  x += __shfl_xor(x, 8, 64);
  x += __shfl_xor(x, 16, 64);
  x += __shfl_xor(x, 32, 64);
  if ((tid & 63) == 0) wavesum[wid] = x;
  __syncthreads();
  if (tid == 0) {
    float tot = 0.f;
    #pragma unroll
    for (int wv = 0; wv < 8; ++wv) tot += wavesum[wv];
    double den = Cacc + (double)__logf(tot);
    atomicAdd(acc, (double)num_b - den);
  }
}

__global__ void crf_finalize(const double* __restrict__ acc, float* __restrict__ out) {
  out[0] = (float)acc[0];
}

extern "C" void kernel_launch(void* const* d_in, const int* in_sizes, int n_in,
                              void* d_out, int out_size, void* d_ws, size_t ws_size,
                              hipStream_t stream) {
  const float* em    = (const float*)d_in[0];
  const int*   tags  = (const int*)d_in[1];
  const unsigned char* mask = (const unsigned char*)d_in[2];
  const float* startt = (const float*)d_in[3];
  const float* endt   = (const float*)d_in[4];
  const float* trans  = (const float*)d_in[5];
  double* acc = (double*)d_ws;

  hipMemsetAsync(d_ws, 0, sizeof(double), stream);
  crf_main<<<256, 512, 0, stream>>>(em, tags, mask, startt, endt, trans, acc);
  crf_finalize<<<1, 1, 0, stream>>>(acc, (float*)d_out);
}

// Round 5
// 326.300 us; speedup vs baseline: 1.0707x; 1.0707x over previous
//
#include <hip/hip_runtime.h>
#include <hip/hip_bf16.h>

// CRF forward (torchcrf, reduction='sum') on MI355X. T=512, B=256, K=128.
// Denominator: 511 sequential steps of s' = (s @ E) * exp(em_t), E = exp(trans)
// in NAMED float2 VGPRs (round-3 array version spilled to scratch: VGPR_Count=40).
// Deferred renorm every 4 steps (publish pre-barrier, apply next step, fp64 log acc).
// Hot loop uses a RAW barrier (lgkmcnt(0) + s_barrier, no vmcnt drain) so the
// 6-deep emission prefetch stays in flight across steps — __syncthreads() was
// draining vmcnt(0) every step, serializing an HBM round-trip into each iteration.
// Layout: 1 chain/block (256 blocks), 512 threads (2 waves/SIMD). Thread
// (j=tid>>2, q=tid&3): quarter-dot over i in [32q,32q+32), E-quarter in 32 VGPRs.
// s[128] ping-pongs in LDS, quarters skewed at 36-float stride (conflict-free,
// SQ_LDS_BANK_CONFLICT=0 measured).

#define TT 512
#define BB 256
#define KK 128
#define TB 32768  // BB*KK

typedef float f2 __attribute__((ext_vector_type(2)));

#if __has_builtin(__builtin_elementwise_fma)
#define FMA2(a, b, c) __builtin_elementwise_fma((a), (b), (c))
#else
static __device__ __forceinline__ f2 FMA2(f2 a, f2 b, f2 c) {
  f2 r; r.x = fmaf(a.x, b.x, c.x); r.y = fmaf(a.y, b.y, c.y); return r;
}
#endif

// Raw workgroup barrier: waits LDS ops only; leaves global (vmcnt) loads in flight.
#define HOT_BARRIER()                                    \
  do {                                                   \
    asm volatile("s_waitcnt lgkmcnt(0)" ::: "memory");   \
    __builtin_amdgcn_s_barrier();                        \
    asm volatile("" ::: "memory");                       \
  } while (0)

__global__ __launch_bounds__(512) void crf_main(
    const float* __restrict__ em,               // [T,B,K]
    const int* __restrict__ tags_raw,           // int32 or int64 [T,B] (detected)
    const unsigned char* __restrict__ mask_raw, // bool bytes or int32 [T,B] (detected)
    const float* __restrict__ startt,           // [K]
    const float* __restrict__ endt,             // [K]
    const float* __restrict__ trans,            // [K,K]
    double* __restrict__ acc)                   // ws accumulator (memset 0)
{
  const int b = blockIdx.x;
  const int tid = threadIdx.x;
  const int j = tid >> 2;        // 0..127 output tag
  const int q = tid & 3;         // quarter of K_prev axis
  const int wid = tid >> 6;      // wave 0..7
  const int qown = j >> 5;       // which quad lane stores s[j]

  __shared__ __align__(16) float srep[2][144];   // skewed: quarter q at [q*36, q*36+32)
  __shared__ __align__(16) float wavesum[16];
  __shared__ int sflags[4];
  __shared__ unsigned char smask[TT];

  // ---- dtype detection ----
  // tags int64 (jax x64): odd int32 words all zero (tags<128). int32: random tags.
  {
    int wv = (tid < 64) ? tags_raw[2 * tid + 1] : 0;
    unsigned long long bal = __ballot(wv != 0);
    if (tid == 0) {
      sflags[0] = (bal == 0ull) ? 1 : 0;        // 1 => int64 tags
      sflags[1] = (mask_raw[1] != 0) ? 0 : 1;   // 1 => int32 mask
    }
  }
  __syncthreads();
  const bool tags64 = (sflags[0] != 0);
  const bool mask32 = (sflags[1] != 0);
  const int* mask_i = (const int*)mask_raw;

  auto get_tag = [&](int t) -> int {
    int idx = t * BB + b;
    return tags64 ? tags_raw[2 * idx] : tags_raw[idx];
  };

  // ---- mask column -> LDS (used only for numerator / prefix length L) ----
  {
    int idx = tid * BB + b;
    bool m = mask32 ? (mask_i[idx] != 0) : (mask_raw[idx] != 0);
    smask[tid] = m ? 1 : 0;
  }
  __syncthreads();

  // ---- numerator: gold path score (one t per thread; prefix-contiguous mask) ----
  float ncon = 0.f, mcnt = 0.f;
  {
    const int t = tid;
    int ct = get_tag(t);
    bool m = (smask[t] != 0);
    if (m) mcnt = 1.f;
    if (t == 0) {
      ncon = startt[ct] + em[(size_t)b * KK + ct];
    } else if (m) {
      int pt = get_tag(t - 1);
      ncon = trans[pt * KK + ct] + em[((size_t)t * BB + b) * KK + ct];
    }
  }
  #pragma unroll
  for (int mm = 1; mm < 64; mm <<= 1) {
    ncon += __shfl_xor(ncon, mm, 64);
    mcnt += __shfl_xor(mcnt, mm, 64);
  }
  if ((tid & 63) == 0) {
    wavesum[wid] = ncon;
    wavesum[8 + wid] = mcnt;
  }
  __syncthreads();
  float num_b = 0.f;                     // live only in tid 0
  if (tid == 0) {
    float ns = 0.f, ms = 0.f;
    #pragma unroll
    for (int wv = 0; wv < 8; ++wv) { ns += wavesum[wv]; ms += wavesum[8 + wv]; }
    int L = (int)(ms + 0.5f);
    num_b = ns + endt[get_tag(L - 1)];   // mask[0] always true
    sflags[2] = L;
  }

  // ---- denominator prologue: E quarter-column in NAMED float2 registers ----
  const int bi = q * 32;
  f2 cl0, ch0, cl1, ch1, cl2, ch2, cl3, ch3, cl4, ch4, cl5, ch5, cl6, ch6, cl7, ch7;
  {
    const float* tp0 = trans + (size_t)bi * KK + j;
#define INITC(n)                                        \
    cl##n.x = __expf(tp0[(4 * n + 0) * KK]);            \
    cl##n.y = __expf(tp0[(4 * n + 1) * KK]);            \
    ch##n.x = __expf(tp0[(4 * n + 2) * KK]);            \
    ch##n.y = __expf(tp0[(4 * n + 3) * KK]);
    INITC(0) INITC(1) INITC(2) INITC(3) INITC(4) INITC(5) INITC(6) INITC(7)
#undef INITC
  }

  const float* emb = em + (size_t)b * KK + j;
  float e0 = __expf(startt[j] + emb[0]);
  if (q == qown) srep[0][j + 4 * qown] = e0;

  // em pipeline: pex = exp(em[t]); e1..e5 = raw em[t+1..t+5]
  float pex = __expf(emb[(size_t)1 * TB]);
  float e1 = emb[(size_t)2 * TB];
  float e2 = emb[(size_t)3 * TB];
  float e3 = emb[(size_t)4 * TB];
  float e4 = emb[(size_t)5 * TB];
  float e5 = emb[(size_t)6 * TB];
  __syncthreads();
  const int L = sflags[2];

  int cur = 0;
  double Cacc = 0.0;                      // used only by tid 0

  for (int t = 1; t < L; ++t) {
    float ecur = pex;                     // exp(em[t]) ready (off critical path)
    pex = __expf(e1);
    e1 = e2; e2 = e3; e3 = e4; e4 = e5;
    int tp = t + 6; if (tp > TT - 1) tp = TT - 1;
    e5 = emb[(size_t)tp * TB];            // stays in flight across the raw barrier

    // quarter dot: sum_{i in [32q,32q+32)} s[i] * E[i][j]
    const float4* sp = reinterpret_cast<const float4*>(&srep[cur][q * 36]);
    f2 a01 = {0.f, 0.f}, a23 = {0.f, 0.f};
#define DOT(n)                                           \
    { float4 s4 = sp[n];                                 \
      f2 slo = {s4.x, s4.y}; f2 shi = {s4.z, s4.w};      \
      a01 = FMA2(slo, cl##n, a01);                       \
      a23 = FMA2(shi, ch##n, a23); }
    DOT(0) DOT(1) DOT(2) DOT(3) DOT(4) DOT(5) DOT(6) DOT(7)
#undef DOT
    float v = (a01.x + a23.x) + (a01.y + a23.y);
    v += __shfl_xor(v, 1, 64);            // intra-quad combine (cheap)
    v += __shfl_xor(v, 2, 64);
    float w = v * ecur;

    if ((t & 3) == 1 && t != 1) {
      // apply deferred normalizer published at t-1 (read is post-barrier of t-1)
      float4 wa = *reinterpret_cast<const float4*>(&wavesum[0]);
      float4 wb = *reinterpret_cast<const float4*>(&wavesum[4]);
      float tot = ((wa.x + wa.y) + (wa.z + wa.w)) + ((wb.x + wb.y) + (wb.z + wb.w));
      if (tid == 0) Cacc += (double)__logf(tot);
      w *= __builtin_amdgcn_rcpf(tot);    // eps telescopes into next log window
    }
    if (q == qown) srep[cur ^ 1][j + 4 * qown] = w;
    if ((t & 3) == 0) {
      // publish partial sums for application at t+1 (pre-barrier write)
      float r = w;
      r += __shfl_xor(r, 4, 64);
      r += __shfl_xor(r, 8, 64);
      r += __shfl_xor(r, 16, 64);
      r += __shfl_xor(r, 32, 64);
      if ((tid & 63) == 0) wavesum[wid] = r;
    }
    HOT_BARRIER();                        // lgkmcnt only — vmcnt stays outstanding
    cur ^= 1;
  }

  // ---- final: den = Cacc + log(sum_j s[j]*exp(end[j])) ----
  float x = srep[cur][j + 4 * qown] * __expf(endt[j]);
  x += __shfl_xor(x, 4, 64);
  x += __shfl_xor(x, 8, 64);
  x += __shfl_xor(x, 16, 64);
  x += __shfl_xor(x, 32, 64);
  if ((tid & 63) == 0) wavesum[wid] = x;
  __syncthreads();
  if (tid == 0) {
    float tot = 0.f;
    #pragma unroll
    for (int wv = 0; wv < 8; ++wv) tot += wavesum[wv];
    double den = Cacc + (double)__logf(tot);
    atomicAdd(acc, (double)num_b - den);
  }
}

__global__ void crf_finalize(const double* __restrict__ acc, float* __restrict__ out) {
  out[0] = (float)acc[0];
}

extern "C" void kernel_launch(void* const* d_in, const int* in_sizes, int n_in,
                              void* d_out, int out_size, void* d_ws, size_t ws_size,
                              hipStream_t stream) {
  const float* em    = (const float*)d_in[0];
  const int*   tags  = (const int*)d_in[1];
  const unsigned char* mask = (const unsigned char*)d_in[2];
  const float* startt = (const float*)d_in[3];
  const float* endt   = (const float*)d_in[4];
  const float* trans  = (const float*)d_in[5];
  double* acc = (double*)d_ws;

  hipMemsetAsync(d_ws, 0, sizeof(double), stream);
  crf_main<<<256, 512, 0, stream>>>(em, tags, mask, startt, endt, trans, acc);
  crf_finalize<<<1, 1, 0, stream>>>(acc, (float*)d_out);
}